// Round 4
// baseline (133.894 us; speedup 1.0000x reference)
//
#include <hip/hip_runtime.h>
#include <math.h>

// Problem constants (fixed by the reference).
#define BB 8
#define LL 12
#define TT 36
#define DD 1024
#define CC 32

// ---------------------------------------------------------------------------
// Single fused kernel, STANDARD launch, ZERO inter-block communication.
// (R2: hipLaunchCooperativeKernel silently no-ops under the harness's graph
// capture. R3: flag-spin sync wedged the container — co-residency is not
// guaranteed under rocprof replay. Lesson: each block must be self-contained.)
//
// Grid 768 x 256 (bid = dh*96 + bl -> the 8 dh-siblings of a bl share
// bid%8 = bl%8 -> same XCD -> xh[bl] (442 KB) is pulled into that XCD's L2
// once and re-read L2-hot). 21 KB LDS, __launch_bounds__(256,3): 3 blocks/CU
// as a perf target only — correctness needs nothing co-resident.
//
// Phase A (redundant Z): each block computes ALL 36 Z-tiles of its own bl.
// Wave wid does t = wid*9..wid*9+8 (9 tasks). xl fragment (12 float4/lane)
// loaded ONCE per wave, reused across all 9 tasks. Per task: lane owns 16 d
// as four 4-d chunks at stride 256 (48 B lane stride -> no fetch
// amplification), 9 Z-dots + 3 H-sums, 12-value butterfly, lane 0 writes
// 48 B straight to LDS (no global Zg round-trip, no workspace use at all).
// Redundancy is 8x but Z-work is tiny; the xh re-reads are L2 traffic.
// Wave 0 also reduces xl -> XLs[3] in LDS.
//
// Phase B: identical to the proven R1 k_out body, minus the Zg global load
// (ZS already in LDS) and with XLg replaced by LDS XLs. Softmax prologue,
// P[t][f][c] in LDS as float4 (2 addrs/wave = free broadcast), ring-6
// register prefetch on xh (L2-hot now), acc[4][4], fused residual + bc
// epilogue, float4 stores.
// ---------------------------------------------------------------------------
__global__ __launch_bounds__(256, 3) void k_fused(
    const float* __restrict__ xl, const float* __restrict__ xh,
    const float* __restrict__ Wm, const float* __restrict__ bm,
    const float* __restrict__ Wq, const float* __restrict__ bq,
    const float* __restrict__ Wc, const float* __restrict__ bc,
    float* __restrict__ out) {
  __shared__ __align__(16) float ZS[TT * 16];     // 2.3 KB (12 used / 16)
  __shared__ float S[TT][CC];                     // 4.6 KB
  __shared__ __align__(16) float PS[TT * 3 * CC]; // 13.8 KB
  __shared__ float mxv[CC], inv[CC];
  __shared__ float XLs[4];

  const int tid  = threadIdx.x;
  const int lane = tid & 63;
  const int wid  = tid >> 6;
  const int bl   = blockIdx.x % 96;     // group: same XCD for all 8 dh
  const int dh   = blockIdx.x / 96;     // 128-d slice

  // ------------------------------- Phase A --------------------------------
  {
    const float4* xl4 = (const float4*)xl + (size_t)bl * 768;
    float4 b4[12];                      // xl fragment: load once, reuse 9x
    #pragma unroll
    for (int j = 0; j < 4; ++j)
      #pragma unroll
      for (int i = 0; i < 3; ++i)
        b4[j*3+i] = xl4[3*lane + 192*j + i];
    const float* b = (const float*)b4;

    for (int k = 0; k < 9; ++k) {       // 9 consecutive t per wave
      const int t   = wid * 9 + k;
      const float4* xh4 = (const float4*)xh + ((size_t)bl * TT + t) * 768;

      float4 a4[12];
      #pragma unroll
      for (int j = 0; j < 4; ++j)
        #pragma unroll
        for (int i = 0; i < 3; ++i)
          a4[j*3+i] = xh4[3*lane + 192*j + i];

      float Z00=0,Z01=0,Z02=0,Z10=0,Z11=0,Z12=0,Z20=0,Z21=0,Z22=0;
      float H0=0,H1=0,H2=0;
      const float* a = (const float*)a4;
      #pragma unroll
      for (int q = 0; q < 16; ++q) {    // 16 d per lane, xh/xl pairing matched
        const float x0=a[q*3], x1=a[q*3+1], x2=a[q*3+2];
        const float y0=b[q*3], y1=b[q*3+1], y2=b[q*3+2];
        Z00 = fmaf(x0,y0,Z00); Z01 = fmaf(x0,y1,Z01); Z02 = fmaf(x0,y2,Z02);
        Z10 = fmaf(x1,y0,Z10); Z11 = fmaf(x1,y1,Z11); Z12 = fmaf(x1,y2,Z12);
        Z20 = fmaf(x2,y0,Z20); Z21 = fmaf(x2,y1,Z21); Z22 = fmaf(x2,y2,Z22);
        H0 += x0; H1 += x1; H2 += x2;
      }

      float v[12] = {Z00,Z01,Z02,Z10,Z11,Z12,Z20,Z21,Z22,H0,H1,H2};
      #pragma unroll
      for (int off = 32; off > 0; off >>= 1)
        #pragma unroll
        for (int j = 0; j < 12; ++j) v[j] += __shfl_down(v[j], off);

      if (lane == 0) {
        float4* o = (float4*)&ZS[t * 16];
        o[0] = make_float4(v[0], v[1], v[2],  v[3]);
        o[1] = make_float4(v[4], v[5], v[6],  v[7]);
        o[2] = make_float4(v[8], v[9], v[10], v[11]);
      }
    }

    if (wid == 0) {                     // XLs[g] = sum_d xl[d,g]
      float s0=0.f, s1=0.f, s2=0.f;
      #pragma unroll
      for (int q = 0; q < 16; ++q) {
        s0 += b[q*3]; s1 += b[q*3+1]; s2 += b[q*3+2];
      }
      #pragma unroll
      for (int off = 32; off > 0; off >>= 1) {
        s0 += __shfl_down(s0, off);
        s1 += __shfl_down(s1, off);
        s2 += __shfl_down(s2, off);
      }
      if (lane == 0) { XLs[0] = s0; XLs[1] = s1; XLs[2] = s2; }
    }
  }
  __syncthreads();

  // ------------------------------- Phase B --------------------------------
  const int b  = bl / LL, l = bl % LL;
  const int c  = tid & 31;              // channel for prologue loops
  const int g  = tid & 31;              // 4-d group within the 128-d slice
  const int h5 = tid >> 5;              // 0..7 -> 4 channels
  const int c0 = h5 * 4;
  const int dg = dh * 32 + g;           // global 4-d group (0..255)

  {                                     // S[t][c] = relu(mq[c,t]) from Z/H
    const float XL0 = XLs[0], XL1 = XLs[1], XL2 = XLs[2];
    const float wm0 = Wm[c*3], wm1 = Wm[c*3+1], wm2 = Wm[c*3+2];
    const float wq0 = Wq[c*3], wq1 = Wq[c*3+1], wq2 = Wq[c*3+2];
    const float bqv = bq[c], bmv = bm[c];
    const float K = bmv * (fmaf(wq0, XL0, fmaf(wq1, XL1, wq2 * XL2)) + 1024.f * bqv);
    for (int idx = tid; idx < TT * CC; idx += 256) {
      const int t = idx >> 5;           // c == tid&31 for every iteration
      const float* z = &ZS[t * 16];
      float m = K;
      m = fmaf(wm0, fmaf(wq0, z[0], fmaf(wq1, z[1], fmaf(wq2, z[2], bqv * z[9]))),  m);
      m = fmaf(wm1, fmaf(wq0, z[3], fmaf(wq1, z[4], fmaf(wq2, z[5], bqv * z[10]))), m);
      m = fmaf(wm2, fmaf(wq0, z[6], fmaf(wq1, z[7], fmaf(wq2, z[8], bqv * z[11]))), m);
      S[t][c] = fmaxf(m, 0.f);
    }
  }
  __syncthreads();

  if (tid < CC) {
    float mx = 0.f;                     // relu >= 0 -> valid seed
    #pragma unroll
    for (int t = 0; t < TT; ++t) mx = fmaxf(mx, S[t][tid]);
    float ssum = 0.f;
    #pragma unroll
    for (int t = 0; t < TT; ++t) ssum += __expf(S[t][tid] - mx);
    mxv[tid] = mx;
    inv[tid] = 1.f / ssum;
  }
  __syncthreads();

  {                                     // P[t][f][c] = att * Wc[c][f]
    const float wc0 = Wc[c*3], wc1 = Wc[c*3+1], wc2 = Wc[c*3+2];
    const float mxc = mxv[c], invc = inv[c];
    for (int idx = tid; idx < TT * CC; idx += 256) {
      const int t = idx >> 5;
      const float e = __expf(S[t][c] - mxc) * invc;
      PS[(t*3+0)*CC + c] = e * wc0;
      PS[(t*3+1)*CC + c] = e * wc1;
      PS[(t*3+2)*CC + c] = e * wc2;
    }
  }
  __syncthreads();

  const float4* base = (const float4*)xh + (size_t)bl * TT * 768 + dg * 3;
  float4 buf[6][3];                     // ring-6 prefetch (L2-hot now)
  #pragma unroll
  for (int j = 0; j < 6; ++j)
    #pragma unroll
    for (int i = 0; i < 3; ++i) buf[j][i] = base[(size_t)j * 768 + i];

  float4 ql[3];                         // residual inputs: issue early
  {
    const float4* xl4 = (const float4*)xl + (size_t)bl * 768 + dg * 3;
    #pragma unroll
    for (int i = 0; i < 3; ++i) ql[i] = xl4[i];
  }

  float acc[4][4];
  #pragma unroll
  for (int u = 0; u < 4; ++u)
    #pragma unroll
    for (int dd = 0; dd < 4; ++dd) acc[u][dd] = 0.f;

  const float4* PS4 = (const float4*)PS;
  #pragma unroll
  for (int t = 0; t < TT; ++t) {
    const int sl = t % 6;               // compile-time under full unroll
    float xv[12];
    {
      const float* x = (const float*)buf[sl];
      #pragma unroll
      for (int i = 0; i < 12; ++i) xv[i] = x[i];
    }
    if (t + 6 < TT) {                   // ring prefetch, 6 t ahead
      const float4* p = base + (size_t)(t + 6) * 768;
      #pragma unroll
      for (int i = 0; i < 3; ++i) buf[sl][i] = p[i];
    }
    const float4 P0 = PS4[(t*3+0)*8 + h5];   // 2 addrs/wave: free broadcast
    const float4 P1 = PS4[(t*3+1)*8 + h5];
    const float4 P2 = PS4[(t*3+2)*8 + h5];
    const float p0[4] = {P0.x, P0.y, P0.z, P0.w};
    const float p1[4] = {P1.x, P1.y, P1.z, P1.w};
    const float p2[4] = {P2.x, P2.y, P2.z, P2.w};
    #pragma unroll
    for (int u = 0; u < 4; ++u)
      #pragma unroll
      for (int dd = 0; dd < 4; ++dd)
        acc[u][dd] = fmaf(p0[u], xv[dd*3],
                     fmaf(p1[u], xv[dd*3+1],
                     fmaf(p2[u], xv[dd*3+2], acc[u][dd])));
  }

  // Epilogue: + bc (sum att = 1) + residual q; float4 stores.
  const float* y = (const float*)ql;    // 12 floats = 4 d x 3 f
  #pragma unroll
  for (int u = 0; u < 4; ++u) {
    const int cc = c0 + u;
    const float w0 = Wq[cc*3], w1 = Wq[cc*3+1], w2 = Wq[cc*3+2];
    const float b0 = bq[cc], bcv = bc[cc];
    float4 o;
    o.x = acc[u][0] + bcv + fmaf(w0, y[0], fmaf(w1, y[1],  fmaf(w2, y[2],  b0)));
    o.y = acc[u][1] + bcv + fmaf(w0, y[3], fmaf(w1, y[4],  fmaf(w2, y[5],  b0)));
    o.z = acc[u][2] + bcv + fmaf(w0, y[6], fmaf(w1, y[7],  fmaf(w2, y[8],  b0)));
    o.w = acc[u][3] + bcv + fmaf(w0, y[9], fmaf(w1, y[10], fmaf(w2, y[11], b0)));
    *(float4*)(out + (((size_t)b * CC + cc) * LL + l) * DD + dg * 4) = o;
  }
}

// ---------------------------------------------------------------------------
extern "C" void kernel_launch(void* const* d_in, const int* in_sizes, int n_in,
                              void* d_out, int out_size, void* d_ws, size_t ws_size,
                              hipStream_t stream) {
  const float* xl = (const float*)d_in[0];  // (B,L,D,F)
  const float* xh = (const float*)d_in[1];  // (B,L,T,D,F)
  const float* Wq = (const float*)d_in[2];
  const float* bq = (const float*)d_in[3];
  const float* Wm = (const float*)d_in[4];
  const float* bm = (const float*)d_in[5];
  const float* Wc = (const float*)d_in[6];
  const float* bc = (const float*)d_in[7];
  float* out = (float*)d_out;               // (B,C,L,D)
  (void)d_ws; (void)ws_size;                // no workspace use

  k_fused<<<dim3(BB * LL * 8), dim3(256), 0, stream>>>(
      xl, xh, Wm, bm, Wq, bq, Wc, bc, out);
}

// Round 5
// 118.060 us; speedup vs baseline: 1.1341x; 1.1341x over previous
//
#include <hip/hip_runtime.h>
#include <math.h>

// Problem constants (fixed by the reference).
#define BB 8
#define LL 12
#define TT 36
#define DD 1024
#define CC 32

// ---------------------------------------------------------------------------
// K1: Z[t,f,g] = sum_d xh[t,d,f]*xl[d,g] (9) and H[t,f] = sum_d xh[t,d,f] (3)
// per (bl,t). R5: 128-thread blocks (2 waves) per task, waves split the
// d-range (8 d/lane = 12 float4 loads in flight) -> up to 2x resident waves
// per CU on the cold 42.5 MB HBM read (R1's 64-thr blocks = 3.4 waves/SIMD
// was latency-bound at ~2.8 TB/s). Reduction: 5-level butterfly (offs 32..2;
// lanes 0,1 then hold complementary even/odd-lane half-sums), both lanes
// store 12 partials to LDS in the same instructions, 12-lane final pass sums
// the 4 partials (2 waves x 2 lanes) and stores Zg. DS/block 130 vs 72 --
// paid for by the occupancy gain. t==0 blocks also emit XLg[bl][g] =
// sum_d xl[d,g] (full 6-level butterfly per wave, 2 partials via LDS).
// ---------------------------------------------------------------------------
__global__ __launch_bounds__(128, 8) void k_Z(const float* __restrict__ xl,
                                              const float* __restrict__ xh,
                                              float* __restrict__ Zg,
                                              float* __restrict__ XLg) {
  __shared__ __align__(16) float part[4][12];   // [wave*2+lane][j]
  __shared__ float xpart[2][3];                 // xl-sum partials (t==0 only)
  const int blk  = blockIdx.x;          // bl*TT + t
  const int bl   = blk / TT;
  const int tid  = threadIdx.x;
  const int lane = tid & 63;
  const int w    = tid >> 6;            // wave 0: d-chunks j=0,1; wave 1: j=2,3
  const float4* xh4 = (const float4*)xh + (size_t)blk * 768;
  const float4* xl4 = (const float4*)xl + (size_t)bl  * 768;

  float4 a4[6], b4[6];                  // 12 loads in flight together
  #pragma unroll
  for (int jt = 0; jt < 2; ++jt)
    #pragma unroll
    for (int i = 0; i < 3; ++i)
      a4[jt*3+i] = xh4[3*lane + 192*(2*w + jt) + i];
  #pragma unroll
  for (int jt = 0; jt < 2; ++jt)
    #pragma unroll
    for (int i = 0; i < 3; ++i)
      b4[jt*3+i] = xl4[3*lane + 192*(2*w + jt) + i];

  float Z00=0,Z01=0,Z02=0,Z10=0,Z11=0,Z12=0,Z20=0,Z21=0,Z22=0;
  float H0=0,H1=0,H2=0;
  const float* a = (const float*)a4;
  const float* b = (const float*)b4;
  #pragma unroll
  for (int k = 0; k < 8; ++k) {         // 8 d per lane, xh/xl pairing matched
    const float x0=a[k*3], x1=a[k*3+1], x2=a[k*3+2];
    const float y0=b[k*3], y1=b[k*3+1], y2=b[k*3+2];
    Z00 = fmaf(x0,y0,Z00); Z01 = fmaf(x0,y1,Z01); Z02 = fmaf(x0,y2,Z02);
    Z10 = fmaf(x1,y0,Z10); Z11 = fmaf(x1,y1,Z11); Z12 = fmaf(x1,y2,Z12);
    Z20 = fmaf(x2,y0,Z20); Z21 = fmaf(x2,y1,Z21); Z22 = fmaf(x2,y2,Z22);
    H0 += x0; H1 += x1; H2 += x2;
  }

  float v[12] = {Z00,Z01,Z02,Z10,Z11,Z12,Z20,Z21,Z22,H0,H1,H2};
  #pragma unroll
  for (int off = 32; off >= 2; off >>= 1)   // 5 levels: stop at off=2
    #pragma unroll
    for (int j = 0; j < 12; ++j) v[j] += __shfl_down(v[j], off);

  if (lane < 2) {                       // lanes 0,1: complementary half-sums
    float4* p = (float4*)part[w*2 + lane];
    p[0] = make_float4(v[0], v[1], v[2],  v[3]);
    p[1] = make_float4(v[4], v[5], v[6],  v[7]);
    p[2] = make_float4(v[8], v[9], v[10], v[11]);
  }

  const bool isT0 = (blk == bl * TT);
  if (isT0) {                           // t == 0: also reduce xl -> XLg
    float s0=0.f, s1=0.f, s2=0.f;
    #pragma unroll
    for (int k = 0; k < 8; ++k) {
      s0 += b[k*3]; s1 += b[k*3+1]; s2 += b[k*3+2];
    }
    #pragma unroll
    for (int off = 32; off > 0; off >>= 1) {
      s0 += __shfl_down(s0, off);
      s1 += __shfl_down(s1, off);
      s2 += __shfl_down(s2, off);
    }
    if (lane == 0) { xpart[w][0] = s0; xpart[w][1] = s1; xpart[w][2] = s2; }
  }
  __syncthreads();

  if (tid < 12) {
    const float s = part[0][tid] + part[1][tid] + part[2][tid] + part[3][tid];
    Zg[(size_t)blk * 16 + tid] = s;
  }
  if (isT0 && tid < 3)
    XLg[bl*4 + tid] = xpart[0][tid] + xpart[1][tid];
}

// ---------------------------------------------------------------------------
// K2 (byte-identical to the R1 k_out, 115.5 us measured): per-block softmax
// prologue from Zg then o[c,d] = sum_t sum_f att[t,c]*Wc[c,f]*xh[t,d,f];
// out = o + bc + q. grid (96, 8) = 768 blocks = EXACTLY 3 blocks/CU. 256 thr
// = (g = tid&31: 4-d group of the 128-d slice) x (h5 = tid>>5: 4 channels).
// Half-wave coalesced xh loads (512B/instr), ring-6 register prefetch, P in
// LDS as [t][f][c4] float4 (2 distinct addrs/wave = free broadcast),
// acc[4][4]; residual xl load hoisted above the t-loop.
// ---------------------------------------------------------------------------
__global__ __launch_bounds__(256, 3) void k_out(const float* __restrict__ xl,
                                                const float* __restrict__ xh,
                                                const float* __restrict__ Zg,
                                                const float* __restrict__ XLg,
                                                const float* __restrict__ Wm,
                                                const float* __restrict__ bm,
                                                const float* __restrict__ Wq,
                                                const float* __restrict__ bq,
                                                const float* __restrict__ Wc,
                                                const float* __restrict__ bc,
                                                float* __restrict__ out) {
  __shared__ __align__(16) float ZS[TT * 16];     // 2.3 KB
  __shared__ float S[TT][CC];                     // 4.6 KB
  __shared__ __align__(16) float PS[TT * 3 * CC]; // 13.8 KB
  __shared__ float mxv[CC], inv[CC];
  const int bl = blockIdx.x;
  const int b = bl / LL, l = bl % LL;
  const int dh = blockIdx.y;            // 0..7 (128-d slice)
  const int tid = threadIdx.x;
  const int c = tid & 31;               // channel for prologue loops

  if (tid < TT * 4) ((float4*)ZS)[tid] = ((const float4*)(Zg + (size_t)bl * TT * 16))[tid];
  __syncthreads();

  {                                     // S[t][c] = relu(mq[c,t]) from Z/H
    const float XL0 = XLg[bl*4+0], XL1 = XLg[bl*4+1], XL2 = XLg[bl*4+2];
    const float wm0 = Wm[c*3], wm1 = Wm[c*3+1], wm2 = Wm[c*3+2];
    const float wq0 = Wq[c*3], wq1 = Wq[c*3+1], wq2 = Wq[c*3+2];
    const float bqv = bq[c], bmv = bm[c];
    const float K = bmv * (fmaf(wq0, XL0, fmaf(wq1, XL1, wq2 * XL2)) + 1024.f * bqv);
    for (int idx = tid; idx < TT * CC; idx += 256) {
      const int t = idx >> 5;           // c == tid&31 for every iteration
      const float* z = &ZS[t * 16];
      float m = K;
      m = fmaf(wm0, fmaf(wq0, z[0], fmaf(wq1, z[1], fmaf(wq2, z[2], bqv * z[9]))),  m);
      m = fmaf(wm1, fmaf(wq0, z[3], fmaf(wq1, z[4], fmaf(wq2, z[5], bqv * z[10]))), m);
      m = fmaf(wm2, fmaf(wq0, z[6], fmaf(wq1, z[7], fmaf(wq2, z[8], bqv * z[11]))), m);
      S[t][c] = fmaxf(m, 0.f);
    }
  }
  __syncthreads();

  if (tid < CC) {
    float mx = 0.f;                     // relu >= 0 -> valid seed
    #pragma unroll
    for (int t = 0; t < TT; ++t) mx = fmaxf(mx, S[t][tid]);
    float ssum = 0.f;
    #pragma unroll
    for (int t = 0; t < TT; ++t) ssum += __expf(S[t][tid] - mx);
    mxv[tid] = mx;
    inv[tid] = 1.f / ssum;
  }
  __syncthreads();

  {                                     // P[t][f][c] = att * Wc[c][f]
    const float wc0 = Wc[c*3], wc1 = Wc[c*3+1], wc2 = Wc[c*3+2];
    const float mxc = mxv[c], invc = inv[c];
    for (int idx = tid; idx < TT * CC; idx += 256) {
      const int t = idx >> 5;
      const float e = __expf(S[t][c] - mxc) * invc;
      PS[(t*3+0)*CC + c] = e * wc0;
      PS[(t*3+1)*CC + c] = e * wc1;
      PS[(t*3+2)*CC + c] = e * wc2;
    }
  }
  __syncthreads();

  const int g  = tid & 31;              // 4-d group within the 128-d slice
  const int h5 = tid >> 5;              // 0..7 -> 4 channels
  const int c0 = h5 * 4;
  const int dg = dh * 32 + g;           // global 4-d group (0..255)

  const float4* base = (const float4*)xh + (size_t)bl * TT * 768 + dg * 3;
  float4 buf[6][3];                     // ring-6 prefetch
  #pragma unroll
  for (int j = 0; j < 6; ++j)
    #pragma unroll
    for (int i = 0; i < 3; ++i) buf[j][i] = base[(size_t)j * 768 + i];

  float4 ql[3];                         // residual inputs: issue early
  {
    const float4* xl4 = (const float4*)xl + (size_t)bl * 768 + dg * 3;
    #pragma unroll
    for (int i = 0; i < 3; ++i) ql[i] = xl4[i];
  }

  float acc[4][4];
  #pragma unroll
  for (int u = 0; u < 4; ++u)
    #pragma unroll
    for (int dd = 0; dd < 4; ++dd) acc[u][dd] = 0.f;

  const float4* PS4 = (const float4*)PS;
  #pragma unroll
  for (int t = 0; t < TT; ++t) {
    const int sl = t % 6;               // compile-time under full unroll
    float xv[12];
    {
      const float* x = (const float*)buf[sl];
      #pragma unroll
      for (int i = 0; i < 12; ++i) xv[i] = x[i];
    }
    if (t + 6 < TT) {                   // ring prefetch, 6 t ahead
      const float4* p = base + (size_t)(t + 6) * 768;
      #pragma unroll
      for (int i = 0; i < 3; ++i) buf[sl][i] = p[i];
    }
    const float4 P0 = PS4[(t*3+0)*8 + h5];   // 2 addrs/wave: free broadcast
    const float4 P1 = PS4[(t*3+1)*8 + h5];
    const float4 P2 = PS4[(t*3+2)*8 + h5];
    const float p0[4] = {P0.x, P0.y, P0.z, P0.w};
    const float p1[4] = {P1.x, P1.y, P1.z, P1.w};
    const float p2[4] = {P2.x, P2.y, P2.z, P2.w};
    #pragma unroll
    for (int u = 0; u < 4; ++u)
      #pragma unroll
      for (int dd = 0; dd < 4; ++dd)
        acc[u][dd] = fmaf(p0[u], xv[dd*3],
                     fmaf(p1[u], xv[dd*3+1],
                     fmaf(p2[u], xv[dd*3+2], acc[u][dd])));
  }

  // Epilogue: + bc (sum att = 1) + residual q; float4 stores.
  const float* y = (const float*)ql;    // 12 floats = 4 d x 3 f
  #pragma unroll
  for (int u = 0; u < 4; ++u) {
    const int cc = c0 + u;
    const float w0 = Wq[cc*3], w1 = Wq[cc*3+1], w2 = Wq[cc*3+2];
    const float b0 = bq[cc], bcv = bc[cc];
    float4 o;
    o.x = acc[u][0] + bcv + fmaf(w0, y[0], fmaf(w1, y[1],  fmaf(w2, y[2],  b0)));
    o.y = acc[u][1] + bcv + fmaf(w0, y[3], fmaf(w1, y[4],  fmaf(w2, y[5],  b0)));
    o.z = acc[u][2] + bcv + fmaf(w0, y[6], fmaf(w1, y[7],  fmaf(w2, y[8],  b0)));
    o.w = acc[u][3] + bcv + fmaf(w0, y[9], fmaf(w1, y[10], fmaf(w2, y[11], b0)));
    *(float4*)(out + (((size_t)b * CC + cc) * LL + l) * DD + dg * 4) = o;
  }
}

// ---------------------------------------------------------------------------
extern "C" void kernel_launch(void* const* d_in, const int* in_sizes, int n_in,
                              void* d_out, int out_size, void* d_ws, size_t ws_size,
                              hipStream_t stream) {
  const float* xl = (const float*)d_in[0];  // (B,L,D,F)
  const float* xh = (const float*)d_in[1];  // (B,L,T,D,F)
  const float* Wq = (const float*)d_in[2];
  const float* bq = (const float*)d_in[3];
  const float* Wm = (const float*)d_in[4];
  const float* bm = (const float*)d_in[5];
  const float* Wc = (const float*)d_in[6];
  const float* bc = (const float*)d_in[7];
  float* out = (float*)d_out;               // (B,C,L,D)

  float* Zg  = (float*)d_ws;                        // [bl*T][16], 221 KB
  float* XLg = Zg + (size_t)BB * LL * TT * 16;      // [bl][4], 1.5 KB

  k_Z  <<<dim3(BB * LL * TT), 128, 0, stream>>>(xl, xh, Zg, XLg);
  k_out<<<dim3(BB * LL, 8),   256, 0, stream>>>(xl, xh, Zg, XLg, Wm, bm, Wq, bq,
                                                Wc, bc, out);
}

// Round 6
// 115.408 us; speedup vs baseline: 1.1602x; 1.0230x over previous
//
#include <hip/hip_runtime.h>
#include <math.h>

// Problem constants (fixed by the reference).
#define BB 8
#define LL 12
#define TT 36
#define DD 1024
#define CC 32

// ---------------------------------------------------------------------------
// K1: Z[t,f,g] = sum_d xh[t,d,f]*xl[d,g] (9) and H[t,f] = sum_d xh[t,d,f] (3)
// per (bl,t). One wave per block, 3456 blocks; lane owns 16 d as FOUR 4-d
// chunks at stride 256 (d = 4*lane + 256*j + 0..3). Loads are
// a4[j*3+i] = xh4[3*lane + 192*j + i]: 48 B lane stride, each contiguous
// 3 KB span covered by 3 adjacent instructions -> no HBM fetch
// amplification. 24 float4 loads in flight per wave (R5's 2-wave/12-load
// split measured +2.5 us: occupancy was not the limiter, per-wave fixed
// costs were). 12-value butterfly, lane 0 stores 48 B.
// t==0 blocks additionally emit XLg[bl][g] = sum_d xl[d,g].
// ---------------------------------------------------------------------------
__global__ __launch_bounds__(64) void k_Z(const float* __restrict__ xl,
                                          const float* __restrict__ xh,
                                          float* __restrict__ Zg,
                                          float* __restrict__ XLg) {
  const int blk  = blockIdx.x;          // bl*TT + t
  const int bl   = blk / TT;
  const int lane = threadIdx.x;         // 0..63
  const float4* xh4 = (const float4*)xh + (size_t)blk * 768;
  const float4* xl4 = (const float4*)xl + (size_t)bl  * 768;

  float4 a4[12], b4[12];                // 24 loads in flight together
  #pragma unroll
  for (int j = 0; j < 4; ++j)
    #pragma unroll
    for (int i = 0; i < 3; ++i)
      a4[j*3+i] = xh4[3*lane + 192*j + i];
  #pragma unroll
  for (int j = 0; j < 4; ++j)
    #pragma unroll
    for (int i = 0; i < 3; ++i)
      b4[j*3+i] = xl4[3*lane + 192*j + i];

  float Z00=0,Z01=0,Z02=0,Z10=0,Z11=0,Z12=0,Z20=0,Z21=0,Z22=0;
  float H0=0,H1=0,H2=0;
  const float* a = (const float*)a4;
  const float* b = (const float*)b4;
  #pragma unroll
  for (int k = 0; k < 16; ++k) {        // 16 d per lane (4 per j), xh/xl matched
    const float x0=a[k*3], x1=a[k*3+1], x2=a[k*3+2];
    const float y0=b[k*3], y1=b[k*3+1], y2=b[k*3+2];
    Z00 = fmaf(x0,y0,Z00); Z01 = fmaf(x0,y1,Z01); Z02 = fmaf(x0,y2,Z02);
    Z10 = fmaf(x1,y0,Z10); Z11 = fmaf(x1,y1,Z11); Z12 = fmaf(x1,y2,Z12);
    Z20 = fmaf(x2,y0,Z20); Z21 = fmaf(x2,y1,Z21); Z22 = fmaf(x2,y2,Z22);
    H0 += x0; H1 += x1; H2 += x2;
  }

  float v[12] = {Z00,Z01,Z02,Z10,Z11,Z12,Z20,Z21,Z22,H0,H1,H2};
  #pragma unroll
  for (int off = 32; off > 0; off >>= 1)
    #pragma unroll
    for (int j = 0; j < 12; ++j) v[j] += __shfl_down(v[j], off);

  if (lane == 0) {
    float4* o = (float4*)(Zg + (size_t)blk * 16);
    o[0] = make_float4(v[0], v[1], v[2],  v[3]);
    o[1] = make_float4(v[4], v[5], v[6],  v[7]);
    o[2] = make_float4(v[8], v[9], v[10], v[11]);
  }

  if (blk == bl * TT) {                 // t == 0: also reduce xl -> XLs
    float s0=0.f, s1=0.f, s2=0.f;
    #pragma unroll
    for (int k = 0; k < 16; ++k) {
      s0 += b[k*3]; s1 += b[k*3+1]; s2 += b[k*3+2];
    }
    #pragma unroll
    for (int off = 32; off > 0; off >>= 1) {
      s0 += __shfl_down(s0, off);
      s1 += __shfl_down(s1, off);
      s2 += __shfl_down(s2, off);
    }
    if (lane == 0) {
      XLg[bl*4+0] = s0; XLg[bl*4+1] = s1; XLg[bl*4+2] = s2;
    }
  }
}

// ---------------------------------------------------------------------------
// K2 (merged): per-block softmax prologue from Zg (tiny, redundant 8x per bl)
// then o[c,d] = sum_t sum_f att[t,c]*Wc[c,f]*xh[t,d,f]; out = o + bc + q.
// grid (96, 8) = 768 blocks = EXACTLY 3 blocks/CU. 256 thr = (g = tid&31:
// 4-d group of the 128-d slice) x (h5 = tid>>5: 4 channels). Half-wave
// coalesced xh loads (512B/instr), ring-6 register prefetch, P in LDS as
// [t][f][c4] float4 (2 distinct addrs/wave = free broadcast), acc[4][4];
// residual xl load hoisted above the t-loop so its latency hides under the
// MACs. __launch_bounds__(256,3) pins VGPR so 3 blocks/CU stay resident.
// ---------------------------------------------------------------------------
__global__ __launch_bounds__(256, 3) void k_out(const float* __restrict__ xl,
                                                const float* __restrict__ xh,
                                                const float* __restrict__ Zg,
                                                const float* __restrict__ XLg,
                                                const float* __restrict__ Wm,
                                                const float* __restrict__ bm,
                                                const float* __restrict__ Wq,
                                                const float* __restrict__ bq,
                                                const float* __restrict__ Wc,
                                                const float* __restrict__ bc,
                                                float* __restrict__ out) {
  __shared__ __align__(16) float ZS[TT * 16];     // 2.3 KB
  __shared__ float S[TT][CC];                     // 4.6 KB
  __shared__ __align__(16) float PS[TT * 3 * CC]; // 13.8 KB
  __shared__ float mxv[CC], inv[CC];
  const int bl = blockIdx.x;
  const int b = bl / LL, l = bl % LL;
  const int dh = blockIdx.y;            // 0..7 (128-d slice)
  const int tid = threadIdx.x;
  const int c = tid & 31;               // channel for prologue loops

  if (tid < TT * 4) ((float4*)ZS)[tid] = ((const float4*)(Zg + (size_t)bl * TT * 16))[tid];
  __syncthreads();

  {                                     // S[t][c] = relu(mq[c,t]) from Z/H
    const float XL0 = XLg[bl*4+0], XL1 = XLg[bl*4+1], XL2 = XLg[bl*4+2];
    const float wm0 = Wm[c*3], wm1 = Wm[c*3+1], wm2 = Wm[c*3+2];
    const float wq0 = Wq[c*3], wq1 = Wq[c*3+1], wq2 = Wq[c*3+2];
    const float bqv = bq[c], bmv = bm[c];
    const float K = bmv * (fmaf(wq0, XL0, fmaf(wq1, XL1, wq2 * XL2)) + 1024.f * bqv);
    for (int idx = tid; idx < TT * CC; idx += 256) {
      const int t = idx >> 5;           // c == tid&31 for every iteration
      const float* z = &ZS[t * 16];
      float m = K;
      m = fmaf(wm0, fmaf(wq0, z[0], fmaf(wq1, z[1], fmaf(wq2, z[2], bqv * z[9]))),  m);
      m = fmaf(wm1, fmaf(wq0, z[3], fmaf(wq1, z[4], fmaf(wq2, z[5], bqv * z[10]))), m);
      m = fmaf(wm2, fmaf(wq0, z[6], fmaf(wq1, z[7], fmaf(wq2, z[8], bqv * z[11]))), m);
      S[t][c] = fmaxf(m, 0.f);
    }
  }
  __syncthreads();

  if (tid < CC) {
    float mx = 0.f;                     // relu >= 0 -> valid seed
    #pragma unroll
    for (int t = 0; t < TT; ++t) mx = fmaxf(mx, S[t][tid]);
    float ssum = 0.f;
    #pragma unroll
    for (int t = 0; t < TT; ++t) ssum += __expf(S[t][tid] - mx);
    mxv[tid] = mx;
    inv[tid] = 1.f / ssum;
  }
  __syncthreads();

  {                                     // P[t][f][c] = att * Wc[c][f]
    const float wc0 = Wc[c*3], wc1 = Wc[c*3+1], wc2 = Wc[c*3+2];
    const float mxc = mxv[c], invc = inv[c];
    for (int idx = tid; idx < TT * CC; idx += 256) {
      const int t = idx >> 5;
      const float e = __expf(S[t][c] - mxc) * invc;
      PS[(t*3+0)*CC + c] = e * wc0;
      PS[(t*3+1)*CC + c] = e * wc1;
      PS[(t*3+2)*CC + c] = e * wc2;
    }
  }
  __syncthreads();

  const int g  = tid & 31;              // 4-d group within the 128-d slice
  const int h5 = tid >> 5;              // 0..7 -> 4 channels
  const int c0 = h5 * 4;
  const int dg = dh * 32 + g;           // global 4-d group (0..255)

  const float4* base = (const float4*)xh + (size_t)bl * TT * 768 + dg * 3;
  float4 buf[6][3];                     // ring-6 prefetch
  #pragma unroll
  for (int j = 0; j < 6; ++j)
    #pragma unroll
    for (int i = 0; i < 3; ++i) buf[j][i] = base[(size_t)j * 768 + i];

  // Residual q inputs: issue now, consumed in the epilogue (latency hidden).
  float4 ql[3];
  {
    const float4* xl4 = (const float4*)xl + (size_t)bl * 768 + dg * 3;
    #pragma unroll
    for (int i = 0; i < 3; ++i) ql[i] = xl4[i];
  }

  float acc[4][4];
  #pragma unroll
  for (int u = 0; u < 4; ++u)
    #pragma unroll
    for (int dd = 0; dd < 4; ++dd) acc[u][dd] = 0.f;

  const float4* PS4 = (const float4*)PS;
  #pragma unroll
  for (int t = 0; t < TT; ++t) {
    const int sl = t % 6;               // compile-time under full unroll
    float xv[12];
    {
      const float* x = (const float*)buf[sl];
      #pragma unroll
      for (int i = 0; i < 12; ++i) xv[i] = x[i];
    }
    if (t + 6 < TT) {                   // ring prefetch, 6 t ahead
      const float4* p = base + (size_t)(t + 6) * 768;
      #pragma unroll
      for (int i = 0; i < 3; ++i) buf[sl][i] = p[i];
    }
    const float4 P0 = PS4[(t*3+0)*8 + h5];   // 2 addrs/wave: free broadcast
    const float4 P1 = PS4[(t*3+1)*8 + h5];
    const float4 P2 = PS4[(t*3+2)*8 + h5];
    const float p0[4] = {P0.x, P0.y, P0.z, P0.w};
    const float p1[4] = {P1.x, P1.y, P1.z, P1.w};
    const float p2[4] = {P2.x, P2.y, P2.z, P2.w};
    #pragma unroll
    for (int u = 0; u < 4; ++u)
      #pragma unroll
      for (int dd = 0; dd < 4; ++dd)
        acc[u][dd] = fmaf(p0[u], xv[dd*3],
                     fmaf(p1[u], xv[dd*3+1],
                     fmaf(p2[u], xv[dd*3+2], acc[u][dd])));
  }

  // Epilogue: + bc (sum att = 1) + residual q; float4 stores.
  const float* y = (const float*)ql;    // 12 floats = 4 d x 3 f
  #pragma unroll
  for (int u = 0; u < 4; ++u) {
    const int cc = c0 + u;
    const float w0 = Wq[cc*3], w1 = Wq[cc*3+1], w2 = Wq[cc*3+2];
    const float b0 = bq[cc], bcv = bc[cc];
    float4 o;
    o.x = acc[u][0] + bcv + fmaf(w0, y[0], fmaf(w1, y[1],  fmaf(w2, y[2],  b0)));
    o.y = acc[u][1] + bcv + fmaf(w0, y[3], fmaf(w1, y[4],  fmaf(w2, y[5],  b0)));
    o.z = acc[u][2] + bcv + fmaf(w0, y[6], fmaf(w1, y[7],  fmaf(w2, y[8],  b0)));
    o.w = acc[u][3] + bcv + fmaf(w0, y[9], fmaf(w1, y[10], fmaf(w2, y[11], b0)));
    *(float4*)(out + (((size_t)b * CC + cc) * LL + l) * DD + dg * 4) = o;
  }
}

// ---------------------------------------------------------------------------
extern "C" void kernel_launch(void* const* d_in, const int* in_sizes, int n_in,
                              void* d_out, int out_size, void* d_ws, size_t ws_size,
                              hipStream_t stream) {
  const float* xl = (const float*)d_in[0];  // (B,L,D,F)
  const float* xh = (const float*)d_in[1];  // (B,L,T,D,F)
  const float* Wq = (const float*)d_in[2];
  const float* bq = (const float*)d_in[3];
  const float* Wm = (const float*)d_in[4];
  const float* bm = (const float*)d_in[5];
  const float* Wc = (const float*)d_in[6];
  const float* bc = (const float*)d_in[7];
  float* out = (float*)d_out;               // (B,C,L,D)

  float* Zg  = (float*)d_ws;                        // [bl*T][16], 221 KB
  float* XLg = Zg + (size_t)BB * LL * TT * 16;      // [bl][4], 1.5 KB

  k_Z  <<<dim3(BB * LL * TT), 64,  0, stream>>>(xl, xh, Zg, XLg);
  k_out<<<dim3(BB * LL, 8),   256, 0, stream>>>(xl, xh, Zg, XLg, Wm, bm, Wq, bq,
                                                Wc, bc, out);
}